// Round 3
// baseline (1208.087 us; speedup 1.0000x reference)
//
#include <hip/hip_runtime.h>

#define L_DIM 128
#define BB 8          // real batch rows per block (padded to 16 for MFMA)

typedef _Float16 f16;
typedef _Float16 f16x8 __attribute__((ext_vector_type(8)));
typedef float f32x4 __attribute__((ext_vector_type(4)));

__device__ __forceinline__ float fast_tanh(float x) {
    // tanh(x) = 1 - 2/(1+e^{2x}); e^{2x} = 2^{x*2*log2(e)}
    float e = __builtin_amdgcn_exp2f(x * 2.8853900817779268f);
    float r = __builtin_amdgcn_rcpf(e + 1.0f);
    return fmaf(-2.0f, r, 1.0f);   // large +x -> 1; large -x -> -1
}

__global__ void __launch_bounds__(512, 2)
cde_kernel(const float* __restrict__ coeffs,
           const float* __restrict__ W_init, const float* __restrict__ b_init,
           const float* __restrict__ W1, const float* __restrict__ b1,
           const float* __restrict__ W2, const float* __restrict__ b2,
           const float* __restrict__ W_out, const float* __restrict__ b_out,
           float* __restrict__ out)
{
    // z16 row = 72 f16 = 9 granules (odd), h16 row = 136 f16 = 17 granules (odd)
    // -> ds_read_b128 across the wave lands max 2 lanes per bank group (free).
    __shared__ __align__(16) f16   z16[16][72];        // fp16 z (rows 8-15 = 0, static)
    __shared__ __align__(16) f16   h16[16][136];       // fp16 hidden activations
    __shared__ __align__(16) float dxT[2][3][16][20];  // [buf][which][c][b]; rows 8+ unused
    __shared__ __align__(16) float zf[BB][64];         // epilogue gather

    const int tid  = threadIdx.x;
    const int blk  = blockIdx.x;
    const int lane = tid & 63;
    const int w    = tid >> 6;        // wave 0..7
    const int q    = lane >> 4;       // quarter-wave 0..3
    const int lr   = lane & 15;
    // GEMM2 tile t (0..7): p = t&3 (hh pair), ch = t>>2 (c half).
    // col lr of tile t -> hh = w*8 + 2p + (lr&1), c = ch*8 + (lr>>1).
    // => c-sum = register (over ch) + shfl_xor(2,4,8) over lr>>1. Fully in-wave.
    const int hsel = lr & 1;
    const int cq   = lr >> 1;
    // After lane-compression, this lane owns rows row0, row0+1 (all real, 0..7):
    const int row0 = (q & 1) * 4 + (q >> 1) * 2;   // q: 0->0, 1->4, 2->2, 3->6

    // ---- one-time: weight fragments into registers ----
    f16x8 w2f[8][4];
    float b2r[8];
#pragma unroll
    for (int t8 = 0; t8 < 8; ++t8) {
        const int outc = (w * 8 + 2 * (t8 & 3) + hsel) * 16 + (t8 >> 2) * 8 + cq;
        b2r[t8] = b2[outc];
#pragma unroll
        for (int kc = 0; kc < 4; ++kc) {
            const float* src = W2 + (size_t)outc * 128 + kc * 32 + q * 8;
            f16x8 v;
#pragma unroll
            for (int i = 0; i < 8; ++i) v[i] = (f16)src[i];
            w2f[t8][kc] = v;
        }
    }
    f16x8 w1f[2];
#pragma unroll
    for (int kc = 0; kc < 2; ++kc) {
        const float* src = W1 + (size_t)(w * 16 + lr) * 64 + kc * 32 + q * 8;
        f16x8 v;
#pragma unroll
        for (int i = 0; i < 8; ++i) v[i] = (f16)src[i];
        w1f[kc] = v;
    }
    const float b1r = b1[w * 16 + lr];

    // ---- init: z0 = X0 @ W_init^T + b_init, registers per (row0+j, hh(p)) ----
    float z32r[4][2], ksumr[4][2];
#pragma unroll
    for (int p = 0; p < 4; ++p) {
        const int hhp = w * 8 + 2 * p + hsel;
#pragma unroll
        for (int j = 0; j < 2; ++j) {
            const float* x0 = coeffs + (size_t)(blk * BB + row0 + j) * (L_DIM - 1) * 64;
            float a = b_init[hhp];
#pragma unroll
            for (int c = 0; c < 16; ++c) a = fmaf(x0[c], W_init[hhp * 16 + c], a);
            z32r[p][j] = a;
            ksumr[p][j] = 0.f;
            if (lr < 2) z16[row0 + j][hhp] = (f16)a;    // lr<2 <=> cq==0, hsel==lr
        }
    }
    for (int i = tid; i < 8 * 72; i += 512) z16[8 + i / 72][i % 72] = (f16)0.f;  // pad rows
    if (tid < BB * 16) {   // spline derivs for step 0 -> buffer 0
        const int b = tid >> 4, c = tid & 15;
        const float* seg = coeffs + (size_t)(blk * BB + b) * (L_DIM - 1) * 64;
        float bv = seg[16 + c], cv = seg[32 + c], dv = seg[48 + c];
        dxT[0][0][c][b] = bv;
        dxT[0][1][c][b] = fmaf(0.25f, dv, fmaf(0.5f, cv, bv));
        dxT[0][2][c][b] = seg[64 + 16 + c];
    }
    __syncthreads();

    // ---- main loop: 127 RK4 steps x 4 f-evals, 2 barriers per f-eval ----
    for (int t = 0; t < L_DIM - 1; ++t) {
        const int buf = t & 1;
        float pb = 0.f, pc = 0.f, pd = 0.f, pe = 0.f;   // dxT prefetch (s2 load, s3 write)
#pragma unroll
        for (int s = 0; s < 4; ++s) {
            // Phase A: GEMM1  h = relu(z @ W1^T + b1)
            {
                f16x8 za0 = *(const f16x8*)&z16[lr][q * 8];
                f16x8 za1 = *(const f16x8*)&z16[lr][32 + q * 8];
                f32x4 hacc = {0.f, 0.f, 0.f, 0.f};
                hacc = __builtin_amdgcn_mfma_f32_16x16x32_f16(za0, w1f[0], hacc, 0, 0, 0);
                hacc = __builtin_amdgcn_mfma_f32_16x16x32_f16(za1, w1f[1], hacc, 0, 0, 0);
#pragma unroll
                for (int r = 0; r < 4; ++r)
                    h16[q * 4 + r][w * 16 + lr] = (f16)fmaxf(hacc[r] + b1r, 0.f);
            }
            __syncthreads();

            // Phase B: GEMM2 (+b2 folded into C-init) -> compress -> tanh -> dX -> RK4
            const int ds = (s == 0) ? 0 : ((s == 3) ? 2 : 1);
            f32x4 acc[8];
#pragma unroll
            for (int t8 = 0; t8 < 8; ++t8) {
                const float bv = b2r[t8];
                acc[t8] = (f32x4){bv, bv, bv, bv};
            }
#pragma unroll
            for (int kc = 0; kc < 4; ++kc) {
                f16x8 af = *(const f16x8*)&h16[lr][kc * 32 + q * 8];
#pragma unroll
                for (int t8 = 0; t8 < 8; ++t8)
                    acc[t8] = __builtin_amdgcn_mfma_f32_16x16x32_f16(af, w2f[t8][kc], acc[t8], 0, 0, 0);
            }
            if (s == 2 && t < L_DIM - 2 && tid < 128) {   // issue next-step spline loads
                const int b = tid >> 4, c = tid & 15;
                const float* seg = coeffs + ((size_t)(blk * BB + b) * (L_DIM - 1) + (t + 1)) * 64;
                pb = seg[16 + c]; pc = seg[32 + c]; pd = seg[48 + c];
                pe = (t + 1 < L_DIM - 2) ? seg[80 + c] : 0.f;
            }
            // Lane-compression: rows 0-7 (all real) live in lanes 0-31's 4 regs;
            // move regs 2,3 to lanes 32-63 so all 64 lanes tanh 2 real elements.
            float ka[4][2] = {{0.f,0.f},{0.f,0.f},{0.f,0.f},{0.f,0.f}};
#pragma unroll
            for (int t8 = 0; t8 < 8; ++t8) {
                float u0 = __shfl_xor(acc[t8][2], 32);
                float u1 = __shfl_xor(acc[t8][3], 32);
                float g0 = (lane < 32) ? acc[t8][0] : u0;
                float g1 = (lane < 32) ? acc[t8][1] : u1;
                g0 = fast_tanh(g0);
                g1 = fast_tanh(g1);
                const float2 dvv = *(const float2*)&dxT[buf][ds][(t8 >> 2) * 8 + cq][row0];
                ka[t8 & 3][0] = fmaf(g0, dvv.x, ka[t8 & 3][0]);
                ka[t8 & 3][1] = fmaf(g1, dvv.y, ka[t8 & 3][1]);
            }
#pragma unroll
            for (int p = 0; p < 4; ++p)
#pragma unroll
                for (int j = 0; j < 2; ++j) {
                    ka[p][j] += __shfl_xor(ka[p][j], 2);
                    ka[p][j] += __shfl_xor(ka[p][j], 4);
                    ka[p][j] += __shfl_xor(ka[p][j], 8);
                }
            // RK4 stage update, in registers (lanes with cq>0 carry redundant copies)
#pragma unroll
            for (int p = 0; p < 4; ++p)
#pragma unroll
                for (int j = 0; j < 2; ++j) {
                    float k = ka[p][j], zs;
                    if (s == 0)      { ksumr[p][j] = k;          zs = fmaf(0.5f, k, z32r[p][j]); }
                    else if (s == 1) { ksumr[p][j] += 2.f * k;   zs = fmaf(0.5f, k, z32r[p][j]); }
                    else if (s == 2) { ksumr[p][j] += 2.f * k;   zs = z32r[p][j] + k; }
                    else { z32r[p][j] = fmaf(ksumr[p][j] + k, 1.f / 6.f, z32r[p][j]); zs = z32r[p][j]; }
                    if (lr < 2) z16[row0 + j][w * 8 + 2 * p + lr] = (f16)zs;
                }
            if (s == 3 && t < L_DIM - 2 && tid < 128) {   // write next-step spline derivs
                const int b = tid >> 4, c = tid & 15;
                dxT[buf ^ 1][0][c][b] = pb;
                dxT[buf ^ 1][1][c][b] = fmaf(0.25f, pd, fmaf(0.5f, pc, pb));
                dxT[buf ^ 1][2][c][b] = (t + 1 < L_DIM - 2) ? pe : (pb + pc + pd);
            }
            __syncthreads();
        }
    }

    // ---- epilogue: out = zT @ W_out^T + b_out ----
    if (lr < 2) {
#pragma unroll
        for (int p = 0; p < 4; ++p)
#pragma unroll
            for (int j = 0; j < 2; ++j)
                zf[row0 + j][w * 8 + 2 * p + lr] = z32r[p][j];
    }
    __syncthreads();
    if (tid < 64) {
        const int b = lane >> 3, j0 = lane & 7;
        float p = 0.f;
#pragma unroll
        for (int m = 0; m < 8; ++m) p += zf[b][j0 + 8 * m] * W_out[j0 + 8 * m];
        p += __shfl_xor(p, 1, 64);
        p += __shfl_xor(p, 2, 64);
        p += __shfl_xor(p, 4, 64);
        if (j0 == 0) out[blk * BB + b] = p + b_out[0];
    }
}

extern "C" void kernel_launch(void* const* d_in, const int* in_sizes, int n_in,
                              void* d_out, int out_size, void* d_ws, size_t ws_size,
                              hipStream_t stream) {
    const float* coeffs = (const float*)d_in[0];
    const float* W_init = (const float*)d_in[1];
    const float* b_init = (const float*)d_in[2];
    const float* W1     = (const float*)d_in[3];
    const float* b1     = (const float*)d_in[4];
    const float* W2     = (const float*)d_in[5];
    const float* b2     = (const float*)d_in[6];
    const float* W_out  = (const float*)d_in[7];
    const float* b_out  = (const float*)d_in[8];
    cde_kernel<<<256, 512, 0, stream>>>(coeffs, W_init, b_init, W1, b1, W2, b2,
                                        W_out, b_out, (float*)d_out);
}

// Round 4
// 1014.997 us; speedup vs baseline: 1.1902x; 1.1902x over previous
//
#include <hip/hip_runtime.h>

#define L_DIM 128
#define BB 8          // real batch rows per block (padded to 16 for MFMA)

typedef _Float16 f16;
typedef _Float16 f16x8 __attribute__((ext_vector_type(8)));
typedef float f32x4 __attribute__((ext_vector_type(4)));

__device__ __forceinline__ float fast_tanh(float x) {
    // tanh(x) = 1 - 2/(1+e^{2x}); e^{2x} = 2^{x*2*log2(e)}
    float e = __builtin_amdgcn_exp2f(x * 2.8853900817779268f);
    float r = __builtin_amdgcn_rcpf(e + 1.0f);
    return fmaf(-2.0f, r, 1.0f);   // large +x -> 1; large -x -> -1
}

// No min-waves arg: r1/r2/r3 showed the allocator caps VGPRs at ~pool/(2*minwaves)
// and spills (WRITE_SIZE 23/93/77 MB of scratch). Demand here is ~215 VGPRs; with the
// cap lifted it fits in 256 -> still 2 waves/SIMD, no spill.
__global__ void __launch_bounds__(512)
cde_kernel(const float* __restrict__ coeffs,
           const float* __restrict__ W_init, const float* __restrict__ b_init,
           const float* __restrict__ W1, const float* __restrict__ b1,
           const float* __restrict__ W2, const float* __restrict__ b2,
           const float* __restrict__ W_out, const float* __restrict__ b_out,
           float* __restrict__ out)
{
    // z16 row = 72 f16 = 9 granules (odd), h16 row = 136 f16 = 17 granules (odd)
    // -> ds_read_b128 across the wave lands max 2 lanes per bank group (free).
    __shared__ __align__(16) f16   z16[16][72];        // fp16 z (rows 8-15 = 0, static)
    __shared__ __align__(16) f16   h16[16][136];       // fp16 hidden activations
    __shared__ __align__(16) float dxT[2][3][16][20];  // [buf][which][c][b]
    __shared__ __align__(16) float zf[BB][64];         // epilogue gather

    const int tid  = threadIdx.x;
    const int blk  = blockIdx.x;
    const int lane = tid & 63;
    const int w    = tid >> 6;        // wave 0..7
    const int q    = lane >> 4;       // quarter-wave 0..3
    const int lr   = lane & 15;
    // GEMM2 tile t8 (0..7): p = t8&3 (hh pair), ch = t8>>2 (c half).
    // col lr of tile -> hh = w*8 + 2p + (lr&1), c = ch*8 + (lr>>1).
    // => c-sum = register (over ch) + shfl_xor(2,4,8) over lr>>1. Fully in-wave.
    const int hsel = lr & 1;
    const int cq   = lr >> 1;
    // After lane-compression, this lane owns rows row0, row0+1 (all real, 0..7):
    const int row0 = (q & 1) * 4 + (q >> 1) * 2;   // q: 0->0, 1->4, 2->2, 3->6

    // ---- one-time: weight fragments into registers ----
    f16x8 w2f[8][4];
    float b2r[8];
#pragma unroll
    for (int t8 = 0; t8 < 8; ++t8) {
        const int outc = (w * 8 + 2 * (t8 & 3) + hsel) * 16 + (t8 >> 2) * 8 + cq;
        b2r[t8] = b2[outc];
#pragma unroll
        for (int kc = 0; kc < 4; ++kc) {
            const float* src = W2 + (size_t)outc * 128 + kc * 32 + q * 8;
            f16x8 v;
#pragma unroll
            for (int i = 0; i < 8; ++i) v[i] = (f16)src[i];
            w2f[t8][kc] = v;
        }
    }
    f16x8 w1f[2];
#pragma unroll
    for (int kc = 0; kc < 2; ++kc) {
        const float* src = W1 + (size_t)(w * 16 + lr) * 64 + kc * 32 + q * 8;
        f16x8 v;
#pragma unroll
        for (int i = 0; i < 8; ++i) v[i] = (f16)src[i];
        w1f[kc] = v;
    }
    const float b1r = b1[w * 16 + lr];

    // ---- init: z0 = X0 @ W_init^T + b_init, registers per (row0+j, hh(p)) ----
    float z32r[4][2], ksumr[4][2];
#pragma unroll
    for (int p = 0; p < 4; ++p) {
        const int hhp = w * 8 + 2 * p + hsel;
#pragma unroll
        for (int j = 0; j < 2; ++j) {
            const float* x0 = coeffs + (size_t)(blk * BB + row0 + j) * (L_DIM - 1) * 64;
            float a = b_init[hhp];
#pragma unroll
            for (int c = 0; c < 16; ++c) a = fmaf(x0[c], W_init[hhp * 16 + c], a);
            z32r[p][j] = a;
            ksumr[p][j] = 0.f;
            if (lr < 2) z16[row0 + j][hhp] = (f16)a;    // lr<2 <=> cq==0, hsel==lr
        }
    }
    for (int i = tid; i < 8 * 72; i += 512) z16[8 + i / 72][i % 72] = (f16)0.f;  // pad rows
    if (tid < BB * 16) {   // spline derivs for step 0 -> buffer 0
        const int b = tid >> 4, c = tid & 15;
        const float* seg = coeffs + (size_t)(blk * BB + b) * (L_DIM - 1) * 64;
        float bv = seg[16 + c], cv = seg[32 + c], dv = seg[48 + c];
        dxT[0][0][c][b] = bv;
        dxT[0][1][c][b] = fmaf(0.25f, dv, fmaf(0.5f, cv, bv));
        dxT[0][2][c][b] = seg[64 + 16 + c];
    }
    __syncthreads();

    // ---- main loop: 127 RK4 steps x 4 f-evals, 2 barriers per f-eval ----
    for (int t = 0; t < L_DIM - 1; ++t) {
        const int buf = t & 1;
        float pb = 0.f, pc = 0.f, pd = 0.f, pe = 0.f;   // dxT prefetch (s2 load, s3 write)
#pragma unroll
        for (int s = 0; s < 4; ++s) {
            // Phase A: GEMM1  h = relu(z @ W1^T + b1)
            {
                f16x8 za0 = *(const f16x8*)&z16[lr][q * 8];
                f16x8 za1 = *(const f16x8*)&z16[lr][32 + q * 8];
                f32x4 hacc = {0.f, 0.f, 0.f, 0.f};
                hacc = __builtin_amdgcn_mfma_f32_16x16x32_f16(za0, w1f[0], hacc, 0, 0, 0);
                hacc = __builtin_amdgcn_mfma_f32_16x16x32_f16(za1, w1f[1], hacc, 0, 0, 0);
#pragma unroll
                for (int r = 0; r < 4; ++r)
                    h16[q * 4 + r][w * 16 + lr] = (f16)fmaxf(hacc[r] + b1r, 0.f);
            }
            __syncthreads();

            // Phase B: GEMM2 (b2 folded into C-init), two c-half passes to cap
            // accumulator pressure at acc[4]; then compress -> tanh -> dX -> RK4.
            const int ds = (s == 0) ? 0 : ((s == 3) ? 2 : 1);
            float ka[4][2] = {{0.f,0.f},{0.f,0.f},{0.f,0.f},{0.f,0.f}};
#pragma unroll
            for (int ch = 0; ch < 2; ++ch) {
                f32x4 acc[4];
#pragma unroll
                for (int p = 0; p < 4; ++p) {
                    const float bv = b2r[ch * 4 + p];
                    acc[p] = (f32x4){bv, bv, bv, bv};
                }
#pragma unroll
                for (int kc = 0; kc < 4; ++kc) {
                    f16x8 af = *(const f16x8*)&h16[lr][kc * 32 + q * 8];
#pragma unroll
                    for (int p = 0; p < 4; ++p)
                        acc[p] = __builtin_amdgcn_mfma_f32_16x16x32_f16(af, w2f[ch * 4 + p][kc], acc[p], 0, 0, 0);
                }
                if (ch == 0 && s == 2 && t < L_DIM - 2 && tid < 128) {  // issue next-step loads
                    const int b = tid >> 4, c = tid & 15;
                    const float* seg = coeffs + ((size_t)(blk * BB + b) * (L_DIM - 1) + (t + 1)) * 64;
                    pb = seg[16 + c]; pc = seg[32 + c]; pd = seg[48 + c];
                    pe = (t + 1 < L_DIM - 2) ? seg[80 + c] : 0.f;
                }
                // Lane-compression: rows 0-7 (all real) live in lanes 0-31's 4 regs;
                // move regs 2,3 to lanes 32-63 so all 64 lanes tanh 2 real elements.
                const float2 dvv = *(const float2*)&dxT[buf][ds][ch * 8 + cq][row0];
#pragma unroll
                for (int p = 0; p < 4; ++p) {
                    float u0 = __shfl_xor(acc[p][2], 32);
                    float u1 = __shfl_xor(acc[p][3], 32);
                    float g0 = (lane < 32) ? acc[p][0] : u0;
                    float g1 = (lane < 32) ? acc[p][1] : u1;
                    g0 = fast_tanh(g0);
                    g1 = fast_tanh(g1);
                    ka[p][0] = fmaf(g0, dvv.x, ka[p][0]);
                    ka[p][1] = fmaf(g1, dvv.y, ka[p][1]);
                }
            }
#pragma unroll
            for (int p = 0; p < 4; ++p)
#pragma unroll
                for (int j = 0; j < 2; ++j) {
                    ka[p][j] += __shfl_xor(ka[p][j], 2);
                    ka[p][j] += __shfl_xor(ka[p][j], 4);
                    ka[p][j] += __shfl_xor(ka[p][j], 8);
                }
            // RK4 stage update, in registers (lanes with cq>0 carry redundant copies)
#pragma unroll
            for (int p = 0; p < 4; ++p)
#pragma unroll
                for (int j = 0; j < 2; ++j) {
                    float k = ka[p][j], zs;
                    if (s == 0)      { ksumr[p][j] = k;          zs = fmaf(0.5f, k, z32r[p][j]); }
                    else if (s == 1) { ksumr[p][j] += 2.f * k;   zs = fmaf(0.5f, k, z32r[p][j]); }
                    else if (s == 2) { ksumr[p][j] += 2.f * k;   zs = z32r[p][j] + k; }
                    else { z32r[p][j] = fmaf(ksumr[p][j] + k, 1.f / 6.f, z32r[p][j]); zs = z32r[p][j]; }
                    if (lr < 2) z16[row0 + j][w * 8 + 2 * p + lr] = (f16)zs;
                }
            if (s == 3 && t < L_DIM - 2 && tid < 128) {   // write next-step spline derivs
                const int b = tid >> 4, c = tid & 15;
                dxT[buf ^ 1][0][c][b] = pb;
                dxT[buf ^ 1][1][c][b] = fmaf(0.25f, pd, fmaf(0.5f, pc, pb));
                dxT[buf ^ 1][2][c][b] = (t + 1 < L_DIM - 2) ? pe : (pb + pc + pd);
            }
            __syncthreads();
        }
    }

    // ---- epilogue: out = zT @ W_out^T + b_out ----
    if (lr < 2) {
#pragma unroll
        for (int p = 0; p < 4; ++p)
#pragma unroll
            for (int j = 0; j < 2; ++j)
                zf[row0 + j][w * 8 + 2 * p + lr] = z32r[p][j];
    }
    __syncthreads();
    if (tid < 64) {
        const int b = lane >> 3, j0 = lane & 7;
        float p = 0.f;
#pragma unroll
        for (int m = 0; m < 8; ++m) p += zf[b][j0 + 8 * m] * W_out[j0 + 8 * m];
        p += __shfl_xor(p, 1, 64);
        p += __shfl_xor(p, 2, 64);
        p += __shfl_xor(p, 4, 64);
        if (j0 == 0) out[blk * BB + b] = p + b_out[0];
    }
}

extern "C" void kernel_launch(void* const* d_in, const int* in_sizes, int n_in,
                              void* d_out, int out_size, void* d_ws, size_t ws_size,
                              hipStream_t stream) {
    const float* coeffs = (const float*)d_in[0];
    const float* W_init = (const float*)d_in[1];
    const float* b_init = (const float*)d_in[2];
    const float* W1     = (const float*)d_in[3];
    const float* b1     = (const float*)d_in[4];
    const float* W2     = (const float*)d_in[5];
    const float* b2     = (const float*)d_in[6];
    const float* W_out  = (const float*)d_in[7];
    const float* b_out  = (const float*)d_in[8];
    cde_kernel<<<256, 512, 0, stream>>>(coeffs, W_init, b_init, W1, b1, W2, b2,
                                        W_out, b_out, (float*)d_out);
}

// Round 5
// 703.542 us; speedup vs baseline: 1.7171x; 1.4427x over previous
//
#include <hip/hip_runtime.h>

#define L_DIM 128
#define BB 8          // real batch rows per block (padded to 16 for MFMA)

typedef _Float16 f16;
typedef _Float16 f16x8 __attribute__((ext_vector_type(8)));
typedef float f32x4 __attribute__((ext_vector_type(4)));

__device__ __forceinline__ float fast_tanh(float x) {
    // tanh(x) = 1 - 2/(1+e^{2x}); e^{2x} = 2^{x*2*log2(e)}
    float e = __builtin_amdgcn_exp2f(x * 2.8853900817779268f);
    float r = __builtin_amdgcn_rcpf(e + 1.0f);
    return fmaf(-2.0f, r, 1.0f);   // large +x -> 1; large -x -> -1
}

// waves_per_eu(2): VGPR budget = 512/2 = 256 per wave (demand ~220) -> no spill,
// 2 waves/SIMD resident (same occupancy as r1-r4, which all reported ~23%).
__attribute__((amdgpu_flat_work_group_size(512, 512), amdgpu_waves_per_eu(2)))
__global__ void
cde_kernel(const float* __restrict__ coeffs,
           const float* __restrict__ W_init, const float* __restrict__ b_init,
           const float* __restrict__ W1, const float* __restrict__ b1,
           const float* __restrict__ W2, const float* __restrict__ b2,
           const float* __restrict__ W_out, const float* __restrict__ b_out,
           float* __restrict__ out)
{
    __shared__ __align__(16) f16   z16[16][72];        // fp16 z (rows 8-15 = 0, static)
    __shared__ __align__(16) f16   h16[16][136];       // fp16 hidden activations
    __shared__ __align__(16) float dxT[2][3][16][20];  // [buf][which][c][b]
    __shared__ __align__(16) float zf[BB][64];         // epilogue gather

    const int tid  = threadIdx.x;
    const int blk  = blockIdx.x;
    const int lane = tid & 63;
    const int w    = tid >> 6;        // wave 0..7
    const int q    = lane >> 4;       // quarter-wave 0..3
    const int lr   = lane & 15;
    // GEMM2 column permutation: col lr of tile tau -> outc = hh*16 + c with
    //   hh = w*8 + (lr&7)   (lane-invariant over tau!)
    //   c  = 2*tau + (lr>>3)
    // => after the tau-register-accumulate, lane holds the 8 same-parity c's of ONE
    //    (b,hh); full c-sum = ONE shfl_xor(8). (r4's 3-chained-shfl tail was the
    //    latency bottleneck: VALUBusy 38% with less VALU work than r1.)
    const int hh   = w * 8 + (lr & 7);
    const int chp  = lr >> 3;
    // After lane-compression, this lane owns rows row0, row0+1 (all real, 0..7):
    const int row0 = (q & 1) * 4 + (q >> 1) * 2;   // q: 0->0, 1->4, 2->2, 3->6

    // ---- one-time: weight fragments into registers ----
    f16x8 w2f[8][4];
    float b2r[8];
#pragma unroll
    for (int t8 = 0; t8 < 8; ++t8) {
        const int outc = hh * 16 + 2 * t8 + chp;
        b2r[t8] = b2[outc];
#pragma unroll
        for (int kc = 0; kc < 4; ++kc) {
            const float* src = W2 + (size_t)outc * 128 + kc * 32 + q * 8;
            f16x8 v;
#pragma unroll
            for (int i = 0; i < 8; ++i) v[i] = (f16)src[i];
            w2f[t8][kc] = v;
        }
    }
    f16x8 w1f[2];
#pragma unroll
    for (int kc = 0; kc < 2; ++kc) {
        const float* src = W1 + (size_t)(w * 16 + lr) * 64 + kc * 32 + q * 8;
        f16x8 v;
#pragma unroll
        for (int i = 0; i < 8; ++i) v[i] = (f16)src[i];
        w1f[kc] = v;
    }
    const float b1r = b1[w * 16 + lr];

    // ---- init: z0 = X0 @ W_init^T + b_init for (b = row0+j, hh) ----
    float z32r[2], ksumr[2];
#pragma unroll
    for (int j = 0; j < 2; ++j) {
        const float* x0 = coeffs + (size_t)(blk * BB + row0 + j) * (L_DIM - 1) * 64;
        float a = b_init[hh];
#pragma unroll
        for (int c = 0; c < 16; ++c) a = fmaf(x0[c], W_init[hh * 16 + c], a);
        z32r[j] = a;
        ksumr[j] = 0.f;
        if (lr < 8) z16[row0 + j][hh] = (f16)a;   // lr<8 <=> chp==0; hh=w*8+lr
    }
    for (int i = tid; i < 8 * 72; i += 512) z16[8 + i / 72][i % 72] = (f16)0.f;  // pad rows
    if (tid < BB * 16) {   // spline derivs for step 0 -> buffer 0
        const int b = tid >> 4, c = tid & 15;
        const float* seg = coeffs + (size_t)(blk * BB + b) * (L_DIM - 1) * 64;
        float bv = seg[16 + c], cv = seg[32 + c], dv = seg[48 + c];
        dxT[0][0][c][b] = bv;
        dxT[0][1][c][b] = fmaf(0.25f, dv, fmaf(0.5f, cv, bv));
        dxT[0][2][c][b] = seg[64 + 16 + c];
    }
    __syncthreads();

    // ---- main loop: 127 RK4 steps x 4 f-evals, 2 barriers per f-eval ----
    for (int t = 0; t < L_DIM - 1; ++t) {
        const int buf = t & 1;
        float pb = 0.f, pc = 0.f, pd = 0.f, pe = 0.f;   // dxT prefetch (s2 load, s3 write)
#pragma unroll
        for (int s = 0; s < 4; ++s) {
            // Phase A: GEMM1  h = relu(z @ W1^T + b1)
            {
                f16x8 za0 = *(const f16x8*)&z16[lr][q * 8];
                f16x8 za1 = *(const f16x8*)&z16[lr][32 + q * 8];
                f32x4 hacc = {0.f, 0.f, 0.f, 0.f};
                hacc = __builtin_amdgcn_mfma_f32_16x16x32_f16(za0, w1f[0], hacc, 0, 0, 0);
                hacc = __builtin_amdgcn_mfma_f32_16x16x32_f16(za1, w1f[1], hacc, 0, 0, 0);
#pragma unroll
                for (int r = 0; r < 4; ++r)
                    h16[q * 4 + r][w * 16 + lr] = (f16)fmaxf(hacc[r] + b1r, 0.f);
            }
            __syncthreads();

            // Phase B: GEMM2 (b2 folded into C-init), two 4-tile passes (caps acc
            // pressure); compress -> tanh -> dX-weighted accumulate over tau.
            const int ds = (s == 0) ? 0 : ((s == 3) ? 2 : 1);
            float ka0 = 0.f, ka1 = 0.f;
#pragma unroll
            for (int hf = 0; hf < 2; ++hf) {
                // dX values for this pass's 4 tiles (independent of MFMA - load early)
                float2 dvv[4];
#pragma unroll
                for (int tt = 0; tt < 4; ++tt)
                    dvv[tt] = *(const float2*)&dxT[buf][ds][2 * (hf * 4 + tt) + chp][row0];
                f32x4 acc[4];
#pragma unroll
                for (int tt = 0; tt < 4; ++tt) {
                    const float bv = b2r[hf * 4 + tt];
                    acc[tt] = (f32x4){bv, bv, bv, bv};
                }
#pragma unroll
                for (int kc = 0; kc < 4; ++kc) {
                    f16x8 af = *(const f16x8*)&h16[lr][kc * 32 + q * 8];
#pragma unroll
                    for (int tt = 0; tt < 4; ++tt)
                        acc[tt] = __builtin_amdgcn_mfma_f32_16x16x32_f16(af, w2f[hf * 4 + tt][kc], acc[tt], 0, 0, 0);
                }
                if (hf == 0 && s == 2 && t < L_DIM - 2 && tid < 128) {  // issue next-step loads
                    const int b = tid >> 4, c = tid & 15;
                    const float* seg = coeffs + ((size_t)(blk * BB + b) * (L_DIM - 1) + (t + 1)) * 64;
                    pb = seg[16 + c]; pc = seg[32 + c]; pd = seg[48 + c];
                    pe = (t + 1 < L_DIM - 2) ? seg[80 + c] : 0.f;
                }
                // Lane-compression: rows 0-7 (real) -> all 64 lanes tanh 2 elements.
#pragma unroll
                for (int tt = 0; tt < 4; ++tt) {
                    float u0 = __shfl_xor(acc[tt][2], 32);
                    float u1 = __shfl_xor(acc[tt][3], 32);
                    float g0 = (lane < 32) ? acc[tt][0] : u0;
                    float g1 = (lane < 32) ? acc[tt][1] : u1;
                    g0 = fast_tanh(g0);
                    g1 = fast_tanh(g1);
                    ka0 = fmaf(g0, dvv[tt].x, ka0);
                    ka1 = fmaf(g1, dvv[tt].y, ka1);
                }
            }
            // complete the c-sum: one shuffle (partner lane lr^8 has other parity)
            ka0 += __shfl_xor(ka0, 8);
            ka1 += __shfl_xor(ka1, 8);
            // RK4 stage update in registers (lr^8 pairs carry redundant copies)
#pragma unroll
            for (int j = 0; j < 2; ++j) {
                float k = (j == 0) ? ka0 : ka1, zs;
                if (s == 0)      { ksumr[j] = k;          zs = fmaf(0.5f, k, z32r[j]); }
                else if (s == 1) { ksumr[j] += 2.f * k;   zs = fmaf(0.5f, k, z32r[j]); }
                else if (s == 2) { ksumr[j] += 2.f * k;   zs = z32r[j] + k; }
                else { z32r[j] = fmaf(ksumr[j] + k, 1.f / 6.f, z32r[j]); zs = z32r[j]; }
                if (lr < 8) z16[row0 + j][hh] = (f16)zs;
            }
            if (s == 3 && t < L_DIM - 2 && tid < 128) {   // write next-step spline derivs
                const int b = tid >> 4, c = tid & 15;
                dxT[buf ^ 1][0][c][b] = pb;
                dxT[buf ^ 1][1][c][b] = fmaf(0.25f, pd, fmaf(0.5f, pc, pb));
                dxT[buf ^ 1][2][c][b] = (t + 1 < L_DIM - 2) ? pe : (pb + pc + pd);
            }
            __syncthreads();
        }
    }

    // ---- epilogue: out = zT @ W_out^T + b_out ----
    if (lr < 8) {
#pragma unroll
        for (int j = 0; j < 2; ++j) zf[row0 + j][hh] = z32r[j];
    }
    __syncthreads();
    if (tid < 64) {
        const int b = lane >> 3, j0 = lane & 7;
        float p = 0.f;
#pragma unroll
        for (int m = 0; m < 8; ++m) p += zf[b][j0 + 8 * m] * W_out[j0 + 8 * m];
        p += __shfl_xor(p, 1, 64);
        p += __shfl_xor(p, 2, 64);
        p += __shfl_xor(p, 4, 64);
        if (j0 == 0) out[blk * BB + b] = p + b_out[0];
    }
}

extern "C" void kernel_launch(void* const* d_in, const int* in_sizes, int n_in,
                              void* d_out, int out_size, void* d_ws, size_t ws_size,
                              hipStream_t stream) {
    const float* coeffs = (const float*)d_in[0];
    const float* W_init = (const float*)d_in[1];
    const float* b_init = (const float*)d_in[2];
    const float* W1     = (const float*)d_in[3];
    const float* b1     = (const float*)d_in[4];
    const float* W2     = (const float*)d_in[5];
    const float* b2     = (const float*)d_in[6];
    const float* W_out  = (const float*)d_in[7];
    const float* b_out  = (const float*)d_in[8];
    cde_kernel<<<256, 512, 0, stream>>>(coeffs, W_init, b_init, W1, b1, W2, b2,
                                        W_out, b_out, (float*)d_out);
}